// Round 5
// baseline (426.171 us; speedup 1.0000x reference)
//
#include <hip/hip_runtime.h>
#include <hip/hip_bf16.h>

typedef __attribute__((ext_vector_type(8))) short s16x8;
typedef __attribute__((ext_vector_type(4))) float f32x4;
typedef unsigned short u16;
typedef unsigned int u32;

constexpr int NN = 50000;
constexpr int NE = 600000;

__device__ inline u16 f2b(float x) {
    __hip_bfloat16 h = __float2bfloat16(x);
    return *(u16*)&h;
}
__device__ inline float b2f(u16 s) { return __uint_as_float(((u32)s) << 16); }

__device__ inline s16x8 pack8(float4 a, float4 b) {
    s16x8 r;
    r[0] = (short)f2b(a.x); r[1] = (short)f2b(a.y);
    r[2] = (short)f2b(a.z); r[3] = (short)f2b(a.w);
    r[4] = (short)f2b(b.x); r[5] = (short)f2b(b.y);
    r[6] = (short)f2b(b.z); r[7] = (short)f2b(b.w);
    return r;
}

// ---------------- misc small kernels ----------------

__global__ void k_zero(int* __restrict__ p, int n) {
    int i = blockIdx.x * 256 + threadIdx.x;
    if (i < n) p[i] = 0;
}

// WTin[c][k], k<768: (fc2_w @ relu_w_bot)^T ; 768..783: (fc1_w @ relu_w_top)^T ; 784..799: 0
__global__ void k_win(const float* __restrict__ fc1w, const float* __restrict__ fc2w,
                      const float* __restrict__ reluw, u16* __restrict__ WTin) {
    int c = threadIdx.x;         // 0..127 output col
    int k = blockIdx.x;          // 0..799
    float s = 0.f;
    if (k < 768) {
        for (int j = 0; j < 128; ++j) s += fc2w[k * 128 + j] * reluw[(128 + j) * 128 + c];
    } else if (k < 784) {
        int kk = k - 768;
        for (int j = 0; j < 128; ++j) s += fc1w[kk * 128 + j] * reluw[j * 128 + c];
    }
    WTin[c * 800 + k] = f2b(s);
}

__global__ void k_bcomb(const float* __restrict__ fc1b, const float* __restrict__ fc2b,
                        const float* __restrict__ relub, const float* __restrict__ reluw,
                        float* __restrict__ bcomb) {
    int c = threadIdx.x;
    float s = relub[c];
    for (int j = 0; j < 128; ++j) {
        s += fc1b[j] * reluw[j * 128 + c];
        s += fc2b[j] * reluw[(128 + j) * 128 + c];
    }
    bcomb[c] = s;
}

// WT[c][s] = stacked [wrel(3x128x128); wroot(128x128)] transposed, bf16
__global__ void k_wrg(const float* __restrict__ wrel, const float* __restrict__ wroot,
                      u16* __restrict__ WT) {
    int c = threadIdx.x;   // e index
    int s = blockIdx.x;    // 0..511 stacked row
    float v = (s < 384) ? wrel[(size_t)s * 128 + c] : wroot[(size_t)(s - 384) * 128 + c];
    WT[c * 512 + s] = f2b(v);
}

// ---------------- CSR build ----------------

__global__ void k_hist(const int* __restrict__ ei, const int* __restrict__ et,
                       int* __restrict__ deg_node, int* __restrict__ deg_rel) {
    int e = blockIdx.x * 256 + threadIdx.x;
    if (e >= NE) return;
    int dst = ei[NE + e];
    int r = et[e];
    atomicAdd(&deg_node[dst], 1);
    atomicAdd(&deg_rel[r * NN + dst], 1);
}

__global__ void k_alloc(const int* __restrict__ deg_node, int* __restrict__ baseoff,
                        int* __restrict__ counter) {
    int i = blockIdx.x * 256 + threadIdx.x;
    int lane = threadIdx.x & 63;
    int d = (i < NN) ? deg_node[i] : 0;
    int scan = d;
    for (int off = 1; off < 64; off <<= 1) {
        int t = __shfl_up(scan, off, 64);
        if (lane >= off) scan += t;
    }
    int total = __shfl(scan, 63, 64);
    int wbase = 0;
    if (lane == 63) wbase = atomicAdd(counter, total);
    wbase = __shfl(wbase, 63, 64);
    if (i < NN) baseoff[i] = wbase + scan - d;  // exclusive prefix within wave + global base
}

__global__ void k_norm(const int* __restrict__ deg_rel, float* __restrict__ normf) {
    int i = blockIdx.x * 256 + threadIdx.x;
    if (i < 3 * NN) normf[i] = 1.0f / (float)max(deg_rel[i], 1);
}

__global__ void k_fill(const int* __restrict__ ei, const int* __restrict__ et,
                       const int* __restrict__ baseoff, int* __restrict__ cursor,
                       int* __restrict__ elist) {
    int e = blockIdx.x * 256 + threadIdx.x;
    if (e >= NE) return;
    int dst = ei[NE + e];
    int src = ei[e];
    int r = et[e];
    int pos = atomicAdd(&cursor[dst], 1);
    elist[baseoff[dst] + pos] = src | (r << 20);
}

// ---------------- aggregation (gather over CSR): 1 wave per node, u32 loads ----------------

__global__ __launch_bounds__(64) void k_agg(const u16* __restrict__ x, u16* __restrict__ A,
                                            const int* __restrict__ elist,
                                            const int* __restrict__ baseoff,
                                            const int* __restrict__ deg_node,
                                            const float* __restrict__ normf) {
    int n = blockIdx.x;
    int lane = threadIdx.x;  // 0..63, handles feats 2*lane, 2*lane+1
    float a0x = 0.f, a0y = 0.f, a1x = 0.f, a1y = 0.f, a2x = 0.f, a2y = 0.f;
    int nb = deg_node[n];
    int b0 = baseoff[n];
    for (int i = 0; i < nb; ++i) {
        int p = elist[b0 + i];
        int src = p & 0xFFFFF;
        int r = p >> 20;
        u32 pair = *(const u32*)&x[(size_t)src * 128 + lane * 2];
        float vx = __uint_as_float((pair & 0xFFFFu) << 16);
        float vy = __uint_as_float((pair >> 16) << 16);
        if (r == 0)      { a0x += vx; a0y += vy; }
        else if (r == 1) { a1x += vx; a1y += vy; }
        else             { a2x += vx; a2y += vy; }
    }
    float n0 = normf[n], n1 = normf[NN + n], n2 = normf[2 * NN + n];
    u32* Ao = (u32*)&A[(size_t)n * 384];
    Ao[lane]        = (u32)f2b(a0x * n0) | ((u32)f2b(a0y * n0) << 16);
    Ao[64 + lane]   = (u32)f2b(a1x * n1) | ((u32)f2b(a1y * n1) << 16);
    Ao[128 + lane]  = (u32)f2b(a2x * n2) | ((u32)f2b(a2y * n2) << 16);
}

// ---------------- GEMM: [N, K] x WT^T -> [N,128] bf16 ----------------
// Barrier-free, LDS-free: every lane loads its MFMA fragments (contiguous 16B
// chunks) directly from global. B (<=204KB) is L2-resident and re-read per
// block (~320MB aggregate L2 traffic ~ 9us); A fragment redundancy (4x, one
// per wave) hits L1. No __syncthreads => no vmcnt(0) drains => the compiler
// software-pipelines loads across the fully-unrolled K-loop with counted
// waitcnts. 4 waves/block, each owns a 32x32 output quadrant.
// A row = concat(A1 (K1T k32-tiles), A2 (K2T k32-tiles, first A2V cols valid, rest 0)).
// WT is [128][ldwt] bf16 row-major. Epilogue: +bias, optional leaky-relu.

template <typename TA, int K1T, int K2T, int A2V, bool LRELU>
__global__ __launch_bounds__(256, 4) void k_gemm(const TA* __restrict__ A1, int lda1,
                                                 const TA* __restrict__ A2, int lda2,
                                                 const u16* __restrict__ WT, int ldwt,
                                                 const float* __restrict__ bias,
                                                 u16* __restrict__ out, int N) {
    const int tid = threadIdx.x;
    const int m0 = blockIdx.x * 32;
    const int w = tid >> 6, lane = tid & 63;
    const int lq = lane >> 4, lr = lane & 15;
    constexpr int KT32 = K1T + K2T;

    // A rows this lane reads (clamped; OOB rows never stored)
    const int r0 = min(m0 + lr, N - 1);
    const int r1 = min(m0 + 16 + lr, N - 1);
    const TA* a1p0 = A1 + (size_t)r0 * lda1 + lq * 8;
    const TA* a1p1 = A1 + (size_t)r1 * lda1 + lq * 8;
    const TA* a2p0 = A2 + (size_t)r0 * lda2 + lq * 8;
    const TA* a2p1 = A2 + (size_t)r1 * lda2 + lq * 8;
    // B cols this lane reads
    const u16* bp0 = WT + (size_t)(w * 32 + lr) * ldwt + lq * 8;
    const u16* bp1 = WT + (size_t)(w * 32 + 16 + lr) * ldwt + lq * 8;

    f32x4 acc[2][2] = {};

#pragma unroll
    for (int kt = 0; kt < KT32; ++kt) {
        s16x8 bf0 = *(const s16x8*)(bp0 + kt * 32);
        s16x8 bf1 = *(const s16x8*)(bp1 + kt * 32);
        s16x8 af0, af1;
        if (kt < K1T) {
            if constexpr (sizeof(TA) == 4) {
                const float4* q0 = (const float4*)(a1p0 + kt * 32);
                const float4* q1 = (const float4*)(a1p1 + kt * 32);
                af0 = pack8(q0[0], q0[1]);
                af1 = pack8(q1[0], q1[1]);
            } else {
                af0 = *(const s16x8*)(a1p0 + kt * 32);
                af1 = *(const s16x8*)(a1p1 + kt * 32);
            }
        } else {
            const int k2 = (kt - K1T) * 32;  // + lq*8 already in pointer
            const bool valid = (k2 + lq * 8) < A2V;  // per-lane static-ish (lq)
            if constexpr (sizeof(TA) == 4) {
                float4 z{0.f, 0.f, 0.f, 0.f};
                float4 f00 = z, f01 = z, f10 = z, f11 = z;
                if (valid) {
                    const float4* q0 = (const float4*)(a2p0 + k2);
                    const float4* q1 = (const float4*)(a2p1 + k2);
                    f00 = q0[0]; f01 = q0[1];
                    f10 = q1[0]; f11 = q1[1];
                }
                af0 = pack8(f00, f01);
                af1 = pack8(f10, f11);
            } else {
                af0 = (s16x8){};
                af1 = (s16x8){};
                if (valid) {
                    af0 = *(const s16x8*)(a2p0 + k2);
                    af1 = *(const s16x8*)(a2p1 + k2);
                }
            }
        }
        acc[0][0] = __builtin_amdgcn_mfma_f32_16x16x32_bf16(af0, bf0, acc[0][0], 0, 0, 0);
        acc[0][1] = __builtin_amdgcn_mfma_f32_16x16x32_bf16(af0, bf1, acc[0][1], 0, 0, 0);
        acc[1][0] = __builtin_amdgcn_mfma_f32_16x16x32_bf16(af1, bf0, acc[1][0], 0, 0, 0);
        acc[1][1] = __builtin_amdgcn_mfma_f32_16x16x32_bf16(af1, bf1, acc[1][1], 0, 0, 0);
    }

#pragma unroll
    for (int i = 0; i < 2; ++i) {
#pragma unroll
        for (int q = 0; q < 4; ++q) {
            const int grow = m0 + i * 16 + lq * 4 + q;
            if (grow < N) {
#pragma unroll
                for (int j = 0; j < 2; ++j) {
                    const int col = w * 32 + j * 16 + lr;
                    float v = acc[i][j][q] + bias[col];
                    if (LRELU) v = v > 0.f ? v : 0.01f * v;
                    out[(size_t)grow * 128 + col] = f2b(v);
                }
            }
        }
    }
}

// ---------------- final gather + classifier ----------------

__global__ __launch_bounds__(256) void k_out(const u16* __restrict__ h, const int* __restrict__ idx,
                                             const float* __restrict__ fc3w,
                                             const float* __restrict__ fc3b,
                                             float* __restrict__ out, int M) {
    int w = threadIdx.x >> 6;
    int lane = threadIdx.x & 63;
    int row = blockIdx.x * 4 + w;
    if (row >= M) return;
    int n = idx[row];
    u32 pair = *(const u32*)&h[(size_t)n * 128 + lane * 2];
    float v0 = __uint_as_float((pair & 0xFFFFu) << 16);
    float v1 = __uint_as_float((pair >> 16) << 16);
    float4 wv = *(const float4*)&fc3w[lane * 4];  // rows 2l, 2l+1 of [128,2]
    float s0 = v0 * wv.x + v1 * wv.z;
    float s1 = v0 * wv.y + v1 * wv.w;
    for (int off = 32; off >= 1; off >>= 1) {
        s0 += __shfl_xor(s0, off, 64);
        s1 += __shfl_xor(s1, off, 64);
    }
    if (lane == 0) {
        out[row * 2] = s0 + fc3b[0];
        out[row * 2 + 1] = s1 + fc3b[1];
    }
}

// ---------------- launch ----------------

extern "C" void kernel_launch(void* const* d_in, const int* in_sizes, int n_in,
                              void* d_out, int out_size, void* d_ws, size_t ws_size,
                              hipStream_t stream) {
    const float* vf    = (const float*)d_in[0];
    const float* tf    = (const float*)d_in[1];
    const float* fc1w  = (const float*)d_in[2];
    const float* fc1b  = (const float*)d_in[3];
    const float* fc2w  = (const float*)d_in[4];
    const float* fc2b  = (const float*)d_in[5];
    const float* reluw = (const float*)d_in[6];
    const float* relub = (const float*)d_in[7];
    const float* w1rel = (const float*)d_in[8];
    const float* w1root= (const float*)d_in[9];
    const float* b1    = (const float*)d_in[10];
    const float* w2rel = (const float*)d_in[11];
    const float* w2root= (const float*)d_in[12];
    const float* b2    = (const float*)d_in[13];
    const float* fc3w  = (const float*)d_in[14];
    const float* fc3b  = (const float*)d_in[15];
    const int* ei      = (const int*)d_in[16];
    const int* et      = (const int*)d_in[17];
    const int* idx     = (const int*)d_in[18];
    float* out = (float*)d_out;

    char* W = (char*)d_ws;
    // workspace layout (bytes)
    const size_t OFF_WTIN  = 0;         // 128*800*2 = 204800
    const size_t OFF_WT1   = 204800;    // 131072
    const size_t OFF_WT2   = 335872;    // 131072
    const size_t OFF_BCOMB = 466944;    // 512
    const size_t OFF_DEGN  = 467456;    // 200000
    const size_t OFF_CUR   = 667456;    // 200000
    const size_t OFF_DEGR  = 867456;    // 600000
    const size_t OFF_CNT   = 1467456;   // 4 (contiguous zero region DEGN..CNT = 250001 ints)
    const size_t OFF_BASE  = 1467712;   // 200000
    const size_t OFF_NORM  = 1667712;   // 600000
    const size_t OFF_ELIST = 2267712;   // 2400000
    const size_t OFF_A     = 4667712;   // 50000*384*2 = 38400000
    const size_t OFF_H0    = 43067712;  // 12800000
    const size_t OFF_H1    = 55867712;  // 12800000
    const size_t OFF_H2    = 68667712;  // 12800000 -> total 81467712

    u16* WTin   = (u16*)(W + OFF_WTIN);
    u16* WT1    = (u16*)(W + OFF_WT1);
    u16* WT2    = (u16*)(W + OFF_WT2);
    float* bcomb= (float*)(W + OFF_BCOMB);
    int* degn   = (int*)(W + OFF_DEGN);
    int* cur    = (int*)(W + OFF_CUR);
    int* degr   = (int*)(W + OFF_DEGR);
    int* cnt    = (int*)(W + OFF_CNT);
    int* base   = (int*)(W + OFF_BASE);
    float* normf= (float*)(W + OFF_NORM);
    int* elist  = (int*)(W + OFF_ELIST);
    u16* Abuf   = (u16*)(W + OFF_A);
    u16* h0     = (u16*)(W + OFF_H0);
    u16* h1     = (u16*)(W + OFF_H1);
    u16* h2     = (u16*)(W + OFF_H2);

    const int GRID_GEMM = (NN + 31) / 32;   // 1563 blocks

    // 1. zero the atomic counters region (deg_node | cursor | deg_rel | counter)
    k_zero<<<(250001 + 255) / 256, 256, 0, stream>>>(degn, 250001);

    // 2. weight precompute
    k_win<<<800, 128, 0, stream>>>(fc1w, fc2w, reluw, WTin);
    k_bcomb<<<1, 128, 0, stream>>>(fc1b, fc2b, relub, reluw, bcomb);
    k_wrg<<<512, 128, 0, stream>>>(w1rel, w1root, WT1);
    k_wrg<<<512, 128, 0, stream>>>(w2rel, w2root, WT2);

    // 3. fused input GEMM: h0 = leakyrelu(tf@Wt + vf@Wv + bcomb)
    k_gemm<float, 24, 1, 16, true><<<GRID_GEMM, 256, 0, stream>>>(
        tf, 768, vf, 16, WTin, 800, bcomb, h0, NN);

    // 4. CSR build (shared by both RGCN layers)
    k_hist<<<(NE + 255) / 256, 256, 0, stream>>>(ei, et, degn, degr);
    k_alloc<<<(NN + 255) / 256, 256, 0, stream>>>(degn, base, cnt);
    k_norm<<<(3 * NN + 255) / 256, 256, 0, stream>>>(degr, normf);
    k_fill<<<(NE + 255) / 256, 256, 0, stream>>>(ei, et, base, cur, elist);

    // 5. RGCN layer 1
    k_agg<<<NN, 64, 0, stream>>>(h0, Abuf, elist, base, degn, normf);
    k_gemm<u16, 12, 4, 128, false><<<GRID_GEMM, 256, 0, stream>>>(
        Abuf, 384, h0, 128, WT1, 512, b1, h1, NN);

    // 6. RGCN layer 2
    k_agg<<<NN, 64, 0, stream>>>(h1, Abuf, elist, base, degn, normf);
    k_gemm<u16, 12, 4, 128, false><<<GRID_GEMM, 256, 0, stream>>>(
        Abuf, 384, h1, 128, WT2, 512, b2, h2, NN);

    // 7. classifier on gathered rows
    k_out<<<(10000 + 3) / 4, 256, 0, stream>>>(h2, idx, fc3w, fc3b, out, 10000);
}

// Round 7
// 304.056 us; speedup vs baseline: 1.4016x; 1.4016x over previous
//
#include <hip/hip_runtime.h>
#include <hip/hip_bf16.h>

typedef __attribute__((ext_vector_type(8))) short s16x8;
typedef __attribute__((ext_vector_type(4))) float f32x4;
typedef unsigned short u16;
typedef unsigned int u32;

constexpr int NN = 50000;
constexpr int NE = 600000;

__device__ inline u16 f2b(float x) {
    __hip_bfloat16 h = __float2bfloat16(x);
    return *(u16*)&h;
}

__device__ inline s16x8 pack8(float4 a, float4 b) {
    s16x8 r;
    r[0] = (short)f2b(a.x); r[1] = (short)f2b(a.y);
    r[2] = (short)f2b(a.z); r[3] = (short)f2b(a.w);
    r[4] = (short)f2b(b.x); r[5] = (short)f2b(b.y);
    r[6] = (short)f2b(b.z); r[7] = (short)f2b(b.w);
    return r;
}

// async global->LDS DMA, 16B per lane: LDS dst = wave-uniform base + lane*16,
// global src per-lane.
__device__ inline void gl_lds16(const void* gptr, void* lptr) {
    __builtin_amdgcn_global_load_lds(
        (const __attribute__((address_space(1))) char*)gptr,
        (__attribute__((address_space(3))) char*)lptr, 16, 0, 0);
}

// ---------------- misc small kernels ----------------

__global__ void k_zero(int* __restrict__ p, int n) {
    int i = blockIdx.x * 256 + threadIdx.x;
    if (i < n) p[i] = 0;
}

__global__ void k_padvf(const float* __restrict__ vf, float* __restrict__ vp) {
    int i = blockIdx.x * 256 + threadIdx.x;
    if (i < NN * 32) {
        int n = i >> 5, c = i & 31;
        vp[i] = c < 16 ? vf[n * 16 + c] : 0.f;
    }
}

// WTin[c][k], k<768: (fc2_w @ relu_w_bot)^T ; 768..783: (fc1_w @ relu_w_top)^T ; 784..799: 0
__global__ void k_win(const float* __restrict__ fc1w, const float* __restrict__ fc2w,
                      const float* __restrict__ reluw, u16* __restrict__ WTin) {
    int c = threadIdx.x;         // 0..127 output col
    int k = blockIdx.x;          // 0..799
    float s = 0.f;
    if (k < 768) {
        for (int j = 0; j < 128; ++j) s += fc2w[k * 128 + j] * reluw[(128 + j) * 128 + c];
    } else if (k < 784) {
        int kk = k - 768;
        for (int j = 0; j < 128; ++j) s += fc1w[kk * 128 + j] * reluw[j * 128 + c];
    }
    WTin[c * 800 + k] = f2b(s);
}

__global__ void k_bcomb(const float* __restrict__ fc1b, const float* __restrict__ fc2b,
                        const float* __restrict__ relub, const float* __restrict__ reluw,
                        float* __restrict__ bcomb) {
    int c = threadIdx.x;
    float s = relub[c];
    for (int j = 0; j < 128; ++j) {
        s += fc1b[j] * reluw[j * 128 + c];
        s += fc2b[j] * reluw[(128 + j) * 128 + c];
    }
    bcomb[c] = s;
}

// WT[c][s] = stacked [wrel(3x128x128); wroot(128x128)] transposed, bf16
__global__ void k_wrg(const float* __restrict__ wrel, const float* __restrict__ wroot,
                      u16* __restrict__ WT) {
    int c = threadIdx.x;   // e index
    int s = blockIdx.x;    // 0..511 stacked row
    float v = (s < 384) ? wrel[(size_t)s * 128 + c] : wroot[(size_t)(s - 384) * 128 + c];
    WT[c * 512 + s] = f2b(v);
}

// ---------------- CSR build ----------------

__global__ void k_hist(const int* __restrict__ ei, const int* __restrict__ et,
                       int* __restrict__ deg_node, int* __restrict__ deg_rel) {
    int e = blockIdx.x * 256 + threadIdx.x;
    if (e >= NE) return;
    int dst = ei[NE + e];
    int r = et[e];
    atomicAdd(&deg_node[dst], 1);
    atomicAdd(&deg_rel[r * NN + dst], 1);
}

__global__ void k_alloc(const int* __restrict__ deg_node, int* __restrict__ baseoff,
                        int* __restrict__ counter) {
    int i = blockIdx.x * 256 + threadIdx.x;
    int lane = threadIdx.x & 63;
    int d = (i < NN) ? deg_node[i] : 0;
    int scan = d;
    for (int off = 1; off < 64; off <<= 1) {
        int t = __shfl_up(scan, off, 64);
        if (lane >= off) scan += t;
    }
    int total = __shfl(scan, 63, 64);
    int wbase = 0;
    if (lane == 63) wbase = atomicAdd(counter, total);
    wbase = __shfl(wbase, 63, 64);
    if (i < NN) baseoff[i] = wbase + scan - d;  // exclusive prefix within wave + global base
}

__global__ void k_norm(const int* __restrict__ deg_rel, float* __restrict__ normf) {
    int i = blockIdx.x * 256 + threadIdx.x;
    if (i < 3 * NN) normf[i] = 1.0f / (float)max(deg_rel[i], 1);
}

__global__ void k_fill(const int* __restrict__ ei, const int* __restrict__ et,
                       const int* __restrict__ baseoff, int* __restrict__ cursor,
                       int* __restrict__ elist) {
    int e = blockIdx.x * 256 + threadIdx.x;
    if (e >= NE) return;
    int dst = ei[NE + e];
    int src = ei[e];
    int r = et[e];
    int pos = atomicAdd(&cursor[dst], 1);
    elist[baseoff[dst] + pos] = src | (r << 20);
}

// ---------------- aggregation (gather over CSR): 1 wave per node, u32 loads ----------------

__global__ __launch_bounds__(64) void k_agg(const u16* __restrict__ x, u16* __restrict__ A,
                                            const int* __restrict__ elist,
                                            const int* __restrict__ baseoff,
                                            const int* __restrict__ deg_node,
                                            const float* __restrict__ normf) {
    int n = blockIdx.x;
    int lane = threadIdx.x;  // 0..63, handles feats 2*lane, 2*lane+1
    float a0x = 0.f, a0y = 0.f, a1x = 0.f, a1y = 0.f, a2x = 0.f, a2y = 0.f;
    int nb = deg_node[n];
    int b0 = baseoff[n];
    for (int i = 0; i < nb; ++i) {
        int p = elist[b0 + i];
        int src = p & 0xFFFFF;
        int r = p >> 20;
        u32 pair = *(const u32*)&x[(size_t)src * 128 + lane * 2];
        float vx = __uint_as_float((pair & 0xFFFFu) << 16);
        float vy = __uint_as_float((pair >> 16) << 16);
        if (r == 0)      { a0x += vx; a0y += vy; }
        else if (r == 1) { a1x += vx; a1y += vy; }
        else             { a2x += vx; a2y += vy; }
    }
    float n0 = normf[n], n1 = normf[NN + n], n2 = normf[2 * NN + n];
    u32* Ao = (u32*)&A[(size_t)n * 384];
    Ao[lane]        = (u32)f2b(a0x * n0) | ((u32)f2b(a0y * n0) << 16);
    Ao[64 + lane]   = (u32)f2b(a1x * n1) | ((u32)f2b(a1y * n1) << 16);
    Ao[128 + lane]  = (u32)f2b(a2x * n2) | ((u32)f2b(a2y * n2) << 16);
}

// ---------------- GEMM: [N, 32*(K1T+K2T)] x WT^T -> [N,128] bf16 ----------------
// m97-pattern: global_load_lds(16B) staging, double-buffered LDS, 2-phase loop
// (stage next tile -> compute current -> one barrier). BM=64, 256 thr = 4 waves
// in 2x2; each wave owns a 32x64 output tile (2x4 MFMA frags).
// LDS layouts (per k32-tile):
//   A fp32: [64 rows][8 slots of 16B], slot swizzle: content(row,s)=chunk s^(row&7)
//   A bf16: [64 rows][4 slots of 16B], swizzle: s ^ ((row>>1)&3)
//   B bf16: [128 cols][4 slots of 16B], swizzle: s ^ ((col>>1)&3)
// Swizzle applied on BOTH sides (pre-swizzled global source + swizzled ds_read).

template <typename TA, int K1T, int K2T, bool LRELU>
__global__ __launch_bounds__(256) void k_gemm(const TA* __restrict__ A1, int lda1,
                                              const TA* __restrict__ A2, int lda2,
                                              const u16* __restrict__ WT, int ldwt,
                                              const float* __restrict__ bias,
                                              u16* __restrict__ out, int N) {
    constexpr int KT = K1T + K2T;
    constexpr int ABYTES = 64 * 32 * (int)sizeof(TA);
    constexpr int TILEB = ABYTES + 8192;
    __shared__ alignas(128) char lds[2][TILEB];

    const int tid = threadIdx.x;
    const int m0 = blockIdx.x * 64;
    const int w = tid >> 6, lane = tid & 63;
    const int wr = w >> 1, wc = w & 1;
    const int lq = lane >> 4, lr = lane & 15;

    auto stage = [&](int buf, int kt) {
        char* base = lds[buf];
        // ---- A tile ----
        if constexpr (sizeof(TA) == 4) {
#pragma unroll
            for (int j = 0; j < 2; ++j) {
                int row = w * 16 + j * 8 + (lane >> 3);
                int s = lane & 7;
                int chunk = s ^ (row & 7);
                int rg = min(m0 + row, N - 1);
                const float* g;
                if (kt < K1T) g = (const float*)A1 + (size_t)rg * lda1 + kt * 32 + chunk * 4;
                else          g = (const float*)A2 + (size_t)rg * lda2 + (kt - K1T) * 32 + chunk * 4;
                gl_lds16(g, base + w * 2048 + j * 1024);
            }
        } else {
            int row = w * 16 + (lane >> 2);
            int s = lane & 3;
            int chunk = s ^ ((row >> 1) & 3);
            int rg = min(m0 + row, N - 1);
            const u16* g;
            if (kt < K1T) g = (const u16*)A1 + (size_t)rg * lda1 + kt * 32 + chunk * 8;
            else          g = (const u16*)A2 + (size_t)rg * lda2 + (kt - K1T) * 32 + chunk * 8;
            gl_lds16(g, base + w * 1024);
        }
        // ---- B tile ----
#pragma unroll
        for (int j = 0; j < 2; ++j) {
            int col = w * 32 + j * 16 + (lane >> 2);
            int s = lane & 3;
            int chunk = s ^ ((col >> 1) & 3);
            const u16* g = WT + (size_t)col * ldwt + kt * 32 + chunk * 8;
            gl_lds16(g, base + ABYTES + w * 2048 + j * 1024);
        }
    };

    f32x4 acc[2][4] = {};

    stage(0, 0);
    __syncthreads();
    int cur = 0;
    for (int kt = 0; kt < KT; ++kt) {
        if (kt + 1 < KT) stage(cur ^ 1, kt + 1);  // DMA overlaps compute below
        char* base = lds[cur];
        s16x8 af[2];
#pragma unroll
        for (int i = 0; i < 2; ++i) {
            int row = wr * 32 + i * 16 + lr;
            if constexpr (sizeof(TA) == 4) {
                int m = row & 7;
                float4 f0 = *(const float4*)(base + row * 128 + (((2 * lq) ^ m) * 16));
                float4 f1 = *(const float4*)(base + row * 128 + (((2 * lq + 1) ^ m) * 16));
                af[i] = pack8(f0, f1);
            } else {
                int sl = lq ^ ((row >> 1) & 3);
                af[i] = *(const s16x8*)(base + row * 64 + sl * 16);
            }
        }
#pragma unroll
        for (int j = 0; j < 4; ++j) {
            int col = wc * 64 + j * 16 + lr;
            int sl = lq ^ ((col >> 1) & 3);
            s16x8 bf = *(const s16x8*)(base + ABYTES + col * 64 + sl * 16);
#pragma unroll
            for (int i = 0; i < 2; ++i)
                acc[i][j] = __builtin_amdgcn_mfma_f32_16x16x32_bf16(af[i], bf, acc[i][j], 0, 0, 0);
        }
        __syncthreads();   // drains staging DMA (vmcnt) + ds_reads; next buf ready
        cur ^= 1;
    }

#pragma unroll
    for (int i = 0; i < 2; ++i) {
#pragma unroll
        for (int q = 0; q < 4; ++q) {
            int grow = m0 + wr * 32 + i * 16 + lq * 4 + q;
            if (grow < N) {
#pragma unroll
                for (int j = 0; j < 4; ++j) {
                    int col = wc * 64 + j * 16 + lr;
                    float v = acc[i][j][q] + bias[col];
                    if (LRELU) v = v > 0.f ? v : 0.01f * v;
                    out[(size_t)grow * 128 + col] = f2b(v);
                }
            }
        }
    }
}

// ---------------- final gather + classifier ----------------

__global__ __launch_bounds__(256) void k_out(const u16* __restrict__ h, const int* __restrict__ idx,
                                             const float* __restrict__ fc3w,
                                             const float* __restrict__ fc3b,
                                             float* __restrict__ out, int M) {
    int w = threadIdx.x >> 6;
    int lane = threadIdx.x & 63;
    int row = blockIdx.x * 4 + w;
    if (row >= M) return;
    int n = idx[row];
    u32 pair = *(const u32*)&h[(size_t)n * 128 + lane * 2];
    float v0 = __uint_as_float((pair & 0xFFFFu) << 16);
    float v1 = __uint_as_float((pair >> 16) << 16);
    float4 wv = *(const float4*)&fc3w[lane * 4];  // rows 2l, 2l+1 of [128,2]
    float s0 = v0 * wv.x + v1 * wv.z;
    float s1 = v0 * wv.y + v1 * wv.w;
    for (int off = 32; off >= 1; off >>= 1) {
        s0 += __shfl_xor(s0, off, 64);
        s1 += __shfl_xor(s1, off, 64);
    }
    if (lane == 0) {
        out[row * 2] = s0 + fc3b[0];
        out[row * 2 + 1] = s1 + fc3b[1];
    }
}

// ---------------- launch ----------------

extern "C" void kernel_launch(void* const* d_in, const int* in_sizes, int n_in,
                              void* d_out, int out_size, void* d_ws, size_t ws_size,
                              hipStream_t stream) {
    const float* vf    = (const float*)d_in[0];
    const float* tf    = (const float*)d_in[1];
    const float* fc1w  = (const float*)d_in[2];
    const float* fc1b  = (const float*)d_in[3];
    const float* fc2w  = (const float*)d_in[4];
    const float* fc2b  = (const float*)d_in[5];
    const float* reluw = (const float*)d_in[6];
    const float* relub = (const float*)d_in[7];
    const float* w1rel = (const float*)d_in[8];
    const float* w1root= (const float*)d_in[9];
    const float* b1    = (const float*)d_in[10];
    const float* w2rel = (const float*)d_in[11];
    const float* w2root= (const float*)d_in[12];
    const float* b2    = (const float*)d_in[13];
    const float* fc3w  = (const float*)d_in[14];
    const float* fc3b  = (const float*)d_in[15];
    const int* ei      = (const int*)d_in[16];
    const int* et      = (const int*)d_in[17];
    const int* idx     = (const int*)d_in[18];
    float* out = (float*)d_out;

    char* W = (char*)d_ws;
    // workspace layout (bytes)
    const size_t OFF_WTIN  = 0;         // 128*800*2 = 204800
    const size_t OFF_WT1   = 204800;    // 131072
    const size_t OFF_WT2   = 335872;    // 131072
    const size_t OFF_BCOMB = 466944;    // 512
    const size_t OFF_DEGN  = 467456;    // 200000
    const size_t OFF_CUR   = 667456;    // 200000
    const size_t OFF_DEGR  = 867456;    // 600000
    const size_t OFF_CNT   = 1467456;   // 4 (contiguous zero region DEGN..CNT = 250001 ints)
    const size_t OFF_BASE  = 1467712;   // 200000
    const size_t OFF_NORM  = 1667712;   // 600000
    const size_t OFF_ELIST = 2267712;   // 2400000
    const size_t OFF_A     = 4667712;   // 50000*384*2 = 38400000
    const size_t OFF_H0    = 43067712;  // 12800000
    const size_t OFF_H1    = 55867712;  // 12800000
    const size_t OFF_H2    = 68667712;  // 12800000
    const size_t OFF_VFPAD = 81467712;  // 50000*32*4 = 6400000 -> total 87867712

    u16* WTin   = (u16*)(W + OFF_WTIN);
    u16* WT1    = (u16*)(W + OFF_WT1);
    u16* WT2    = (u16*)(W + OFF_WT2);
    float* bcomb= (float*)(W + OFF_BCOMB);
    int* degn   = (int*)(W + OFF_DEGN);
    int* cur    = (int*)(W + OFF_CUR);
    int* degr   = (int*)(W + OFF_DEGR);
    int* cnt    = (int*)(W + OFF_CNT);
    int* base   = (int*)(W + OFF_BASE);
    float* normf= (float*)(W + OFF_NORM);
    int* elist  = (int*)(W + OFF_ELIST);
    u16* Abuf   = (u16*)(W + OFF_A);
    u16* h0     = (u16*)(W + OFF_H0);
    u16* h1     = (u16*)(W + OFF_H1);
    u16* h2     = (u16*)(W + OFF_H2);
    float* vfp  = (float*)(W + OFF_VFPAD);

    const int GRID_GEMM = (NN + 63) / 64;   // 782 blocks

    // 1. zero atomic counters region (deg_node | cursor | deg_rel | counter); pad vf
    k_zero<<<(250001 + 255) / 256, 256, 0, stream>>>(degn, 250001);
    k_padvf<<<(NN * 32 + 255) / 256, 256, 0, stream>>>(vf, vfp);

    // 2. weight precompute
    k_win<<<800, 128, 0, stream>>>(fc1w, fc2w, reluw, WTin);
    k_bcomb<<<1, 128, 0, stream>>>(fc1b, fc2b, relub, reluw, bcomb);
    k_wrg<<<512, 128, 0, stream>>>(w1rel, w1root, WT1);
    k_wrg<<<512, 128, 0, stream>>>(w2rel, w2root, WT2);

    // 3. fused input GEMM: h0 = leakyrelu(tf@Wt + vf@Wv + bcomb)
    k_gemm<float, 24, 1, true><<<GRID_GEMM, 256, 0, stream>>>(
        tf, 768, vfp, 32, WTin, 800, bcomb, h0, NN);

    // 4. CSR build (shared by both RGCN layers)
    k_hist<<<(NE + 255) / 256, 256, 0, stream>>>(ei, et, degn, degr);
    k_alloc<<<(NN + 255) / 256, 256, 0, stream>>>(degn, base, cnt);
    k_norm<<<(3 * NN + 255) / 256, 256, 0, stream>>>(degr, normf);
    k_fill<<<(NE + 255) / 256, 256, 0, stream>>>(ei, et, base, cur, elist);

    // 5. RGCN layer 1
    k_agg<<<NN, 64, 0, stream>>>(h0, Abuf, elist, base, degn, normf);
    k_gemm<u16, 12, 4, false><<<GRID_GEMM, 256, 0, stream>>>(
        Abuf, 384, h0, 128, WT1, 512, b1, h1, NN);

    // 6. RGCN layer 2
    k_agg<<<NN, 64, 0, stream>>>(h1, Abuf, elist, base, degn, normf);
    k_gemm<u16, 12, 4, false><<<GRID_GEMM, 256, 0, stream>>>(
        Abuf, 384, h1, 128, WT2, 512, b2, h2, NN);

    // 7. classifier on gathered rows
    k_out<<<(10000 + 3) / 4, 256, 0, stream>>>(h2, idx, fc3w, fc3b, out, 10000);
}

// Round 8
// 300.091 us; speedup vs baseline: 1.4201x; 1.0132x over previous
//
#include <hip/hip_runtime.h>
#include <hip/hip_bf16.h>

typedef __attribute__((ext_vector_type(8))) short s16x8;
typedef __attribute__((ext_vector_type(4))) float f32x4;
typedef unsigned short u16;
typedef unsigned int u32;

constexpr int NN = 50000;
constexpr int NE = 600000;

__device__ inline u16 f2b(float x) {
    __hip_bfloat16 h = __float2bfloat16(x);
    return *(u16*)&h;
}

__device__ inline s16x8 pack8(float4 a, float4 b) {
    s16x8 r;
    r[0] = (short)f2b(a.x); r[1] = (short)f2b(a.y);
    r[2] = (short)f2b(a.z); r[3] = (short)f2b(a.w);
    r[4] = (short)f2b(b.x); r[5] = (short)f2b(b.y);
    r[6] = (short)f2b(b.z); r[7] = (short)f2b(b.w);
    return r;
}

// async global->LDS DMA, 16B per lane: LDS dst = wave-uniform base + lane*16.
__device__ inline void gl_lds16(const void* gptr, void* lptr) {
    __builtin_amdgcn_global_load_lds(
        (const __attribute__((address_space(1))) char*)gptr,
        (__attribute__((address_space(3))) char*)lptr, 16, 0, 0);
}

template <int N> __device__ inline void vmwait() {
    asm volatile("s_waitcnt vmcnt(%0)" :: "n"(N) : "memory");
}
__device__ inline void barrier_nodrains() {
    __builtin_amdgcn_sched_barrier(0);
    __builtin_amdgcn_s_barrier();
    __builtin_amdgcn_sched_barrier(0);
}

// ---------------- misc small kernels ----------------

__global__ void k_zero(int* __restrict__ p, int n) {
    int i = blockIdx.x * 256 + threadIdx.x;
    if (i < n) p[i] = 0;
}

__global__ void k_padvf(const float* __restrict__ vf, float* __restrict__ vp) {
    int i = blockIdx.x * 256 + threadIdx.x;
    if (i < NN * 32) {
        int n = i >> 5, c = i & 31;
        vp[i] = c < 16 ? vf[n * 16 + c] : 0.f;
    }
}

// WTin[c][k], k<768: (fc2_w @ relu_w_bot)^T ; 768..783: (fc1_w @ relu_w_top)^T ; 784..799: 0
__global__ void k_win(const float* __restrict__ fc1w, const float* __restrict__ fc2w,
                      const float* __restrict__ reluw, u16* __restrict__ WTin) {
    int c = threadIdx.x;         // 0..127 output col
    int k = blockIdx.x;          // 0..799
    float s = 0.f;
    if (k < 768) {
        for (int j = 0; j < 128; ++j) s += fc2w[k * 128 + j] * reluw[(128 + j) * 128 + c];
    } else if (k < 784) {
        int kk = k - 768;
        for (int j = 0; j < 128; ++j) s += fc1w[kk * 128 + j] * reluw[j * 128 + c];
    }
    WTin[c * 800 + k] = f2b(s);
}

__global__ void k_bcomb(const float* __restrict__ fc1b, const float* __restrict__ fc2b,
                        const float* __restrict__ relub, const float* __restrict__ reluw,
                        float* __restrict__ bcomb) {
    int c = threadIdx.x;
    float s = relub[c];
    for (int j = 0; j < 128; ++j) {
        s += fc1b[j] * reluw[j * 128 + c];
        s += fc2b[j] * reluw[(128 + j) * 128 + c];
    }
    bcomb[c] = s;
}

// WT[c][s] = stacked [wrel(3x128x128); wroot(128x128)] transposed, bf16
__global__ void k_wrg(const float* __restrict__ wrel, const float* __restrict__ wroot,
                      u16* __restrict__ WT) {
    int c = threadIdx.x;   // e index
    int s = blockIdx.x;    // 0..511 stacked row
    float v = (s < 384) ? wrel[(size_t)s * 128 + c] : wroot[(size_t)(s - 384) * 128 + c];
    WT[c * 512 + s] = f2b(v);
}

// ---------------- CSR build ----------------

__global__ void k_hist(const int* __restrict__ ei, const int* __restrict__ et,
                       int* __restrict__ deg_node, int* __restrict__ deg_rel) {
    int e = blockIdx.x * 256 + threadIdx.x;
    if (e >= NE) return;
    int dst = ei[NE + e];
    int r = et[e];
    atomicAdd(&deg_node[dst], 1);
    atomicAdd(&deg_rel[r * NN + dst], 1);
}

__global__ void k_alloc(const int* __restrict__ deg_node, int* __restrict__ baseoff,
                        int* __restrict__ counter) {
    int i = blockIdx.x * 256 + threadIdx.x;
    int lane = threadIdx.x & 63;
    int d = (i < NN) ? deg_node[i] : 0;
    int scan = d;
    for (int off = 1; off < 64; off <<= 1) {
        int t = __shfl_up(scan, off, 64);
        if (lane >= off) scan += t;
    }
    int total = __shfl(scan, 63, 64);
    int wbase = 0;
    if (lane == 63) wbase = atomicAdd(counter, total);
    wbase = __shfl(wbase, 63, 64);
    if (i < NN) baseoff[i] = wbase + scan - d;
}

__global__ void k_norm(const int* __restrict__ deg_rel, float* __restrict__ normf) {
    int i = blockIdx.x * 256 + threadIdx.x;
    if (i < 3 * NN) normf[i] = 1.0f / (float)max(deg_rel[i], 1);
}

__global__ void k_fill(const int* __restrict__ ei, const int* __restrict__ et,
                       const int* __restrict__ baseoff, int* __restrict__ cursor,
                       int* __restrict__ elist) {
    int e = blockIdx.x * 256 + threadIdx.x;
    if (e >= NE) return;
    int dst = ei[NE + e];
    int src = ei[e];
    int r = et[e];
    int pos = atomicAdd(&cursor[dst], 1);
    elist[baseoff[dst] + pos] = src | (r << 20);
}

// ---------------- aggregation (gather over CSR): 1 wave per node, u32 loads ----------------

__global__ __launch_bounds__(64) void k_agg(const u16* __restrict__ x, u16* __restrict__ A,
                                            const int* __restrict__ elist,
                                            const int* __restrict__ baseoff,
                                            const int* __restrict__ deg_node,
                                            const float* __restrict__ normf) {
    int n = blockIdx.x;
    int lane = threadIdx.x;
    float a0x = 0.f, a0y = 0.f, a1x = 0.f, a1y = 0.f, a2x = 0.f, a2y = 0.f;
    int nb = deg_node[n];
    int b0 = baseoff[n];
    for (int i = 0; i < nb; ++i) {
        int p = elist[b0 + i];
        int src = p & 0xFFFFF;
        int r = p >> 20;
        u32 pair = *(const u32*)&x[(size_t)src * 128 + lane * 2];
        float vx = __uint_as_float((pair & 0xFFFFu) << 16);
        float vy = __uint_as_float((pair >> 16) << 16);
        if (r == 0)      { a0x += vx; a0y += vy; }
        else if (r == 1) { a1x += vx; a1y += vy; }
        else             { a2x += vx; a2y += vy; }
    }
    float n0 = normf[n], n1 = normf[NN + n], n2 = normf[2 * NN + n];
    u32* Ao = (u32*)&A[(size_t)n * 384];
    Ao[lane]        = (u32)f2b(a0x * n0) | ((u32)f2b(a0y * n0) << 16);
    Ao[64 + lane]   = (u32)f2b(a1x * n1) | ((u32)f2b(a1y * n1) << 16);
    Ao[128 + lane]  = (u32)f2b(a2x * n2) | ((u32)f2b(a2y * n2) << 16);
}

// ---------------- GEMM: [N, 32*(K1T+K2T)] x WT^T -> [N,128] bf16 ----------------
// Round-7 mapping + T3/T4: 4 LDS buffers, prefetch depth 3, counted vmcnt at the
// barrier (never 0 in the main loop). Per iteration j:
//   vmcnt(2*OPW)  -> stage(j) landed, stages j+1,j+2 stay in flight
//   s_barrier     -> all waves' tile-j data in LDS
//   compute(j)    -> ds_read + 8 MFMA/wave
//   stage(j+3)    -> issue next DMAs (overwrites buf[(j-1)&3]; reads of it done
//                    before any wave passed barrier(j))
// Tail: vmcnt(OPW) then vmcnt(0).

template <typename TA, int K1T, int K2T, bool LRELU>
__global__ __launch_bounds__(256) void k_gemm(const TA* __restrict__ A1, int lda1,
                                              const TA* __restrict__ A2, int lda2,
                                              const u16* __restrict__ WT, int ldwt,
                                              const float* __restrict__ bias,
                                              u16* __restrict__ out, int N) {
    constexpr int KT = K1T + K2T;
    constexpr int ABYTES = 64 * 32 * (int)sizeof(TA);
    constexpr int TILEB = ABYTES + 8192;
    constexpr int OPW = (sizeof(TA) == 4) ? 4 : 3;   // DMA instrs per wave per stage
    __shared__ alignas(128) char lds[4][TILEB];

    const int tid = threadIdx.x;
    const int m0 = blockIdx.x * 64;
    const int w = tid >> 6, lane = tid & 63;
    const int wr = w >> 1, wc = w & 1;
    const int lq = lane >> 4, lr = lane & 15;

    auto stage = [&](int j) {
        char* base = lds[j & 3];
        int kt = j;
        // ---- A tile ----
        if constexpr (sizeof(TA) == 4) {
#pragma unroll
            for (int jj = 0; jj < 2; ++jj) {
                int row = w * 16 + jj * 8 + (lane >> 3);
                int s = lane & 7;
                int chunk = s ^ (row & 7);
                int rg = min(m0 + row, N - 1);
                const float* g;
                if (kt < K1T) g = (const float*)A1 + (size_t)rg * lda1 + kt * 32 + chunk * 4;
                else          g = (const float*)A2 + (size_t)rg * lda2 + (kt - K1T) * 32 + chunk * 4;
                gl_lds16(g, base + w * 2048 + jj * 1024);
            }
        } else {
            int row = w * 16 + (lane >> 2);
            int s = lane & 3;
            int chunk = s ^ ((row >> 1) & 3);
            int rg = min(m0 + row, N - 1);
            const u16* g;
            if (kt < K1T) g = (const u16*)A1 + (size_t)rg * lda1 + kt * 32 + chunk * 8;
            else          g = (const u16*)A2 + (size_t)rg * lda2 + (kt - K1T) * 32 + chunk * 8;
            gl_lds16(g, base + w * 1024);
        }
        // ---- B tile ----
#pragma unroll
        for (int jj = 0; jj < 2; ++jj) {
            int col = w * 32 + jj * 16 + (lane >> 2);
            int s = lane & 3;
            int chunk = s ^ ((col >> 1) & 3);
            const u16* g = WT + (size_t)col * ldwt + kt * 32 + chunk * 8;
            gl_lds16(g, base + ABYTES + w * 2048 + jj * 1024);
        }
    };

    f32x4 acc[2][4] = {};

    auto compute = [&](int j) {
        char* base = lds[j & 3];
        s16x8 af[2];
#pragma unroll
        for (int i = 0; i < 2; ++i) {
            int row = wr * 32 + i * 16 + lr;
            if constexpr (sizeof(TA) == 4) {
                int m = row & 7;
                float4 f0 = *(const float4*)(base + row * 128 + (((2 * lq) ^ m) * 16));
                float4 f1 = *(const float4*)(base + row * 128 + (((2 * lq + 1) ^ m) * 16));
                af[i] = pack8(f0, f1);
            } else {
                int sl = lq ^ ((row >> 1) & 3);
                af[i] = *(const s16x8*)(base + row * 64 + sl * 16);
            }
        }
#pragma unroll
        for (int j4 = 0; j4 < 4; ++j4) {
            int col = wc * 64 + j4 * 16 + lr;
            int sl = lq ^ ((col >> 1) & 3);
            s16x8 bf = *(const s16x8*)(base + ABYTES + col * 64 + sl * 16);
#pragma unroll
            for (int i = 0; i < 2; ++i)
                acc[i][j4] = __builtin_amdgcn_mfma_f32_16x16x32_bf16(af[i], bf, acc[i][j4], 0, 0, 0);
        }
    };

    stage(0); stage(1); stage(2);
    for (int j = 0; j < KT - 2; ++j) {
        vmwait<2 * OPW>();
        barrier_nodrains();
        compute(j);
        if (j + 3 < KT) stage(j + 3);
    }
    vmwait<OPW>();
    barrier_nodrains();
    compute(KT - 2);
    vmwait<0>();
    barrier_nodrains();
    compute(KT - 1);

#pragma unroll
    for (int i = 0; i < 2; ++i) {
#pragma unroll
        for (int q = 0; q < 4; ++q) {
            int grow = m0 + wr * 32 + i * 16 + lq * 4 + q;
            if (grow < N) {
#pragma unroll
                for (int j = 0; j < 4; ++j) {
                    int col = wc * 64 + j * 16 + lr;
                    float v = acc[i][j][q] + bias[col];
                    if (LRELU) v = v > 0.f ? v : 0.01f * v;
                    out[(size_t)grow * 128 + col] = f2b(v);
                }
            }
        }
    }
}

// ---------------- final gather + classifier ----------------

__global__ __launch_bounds__(256) void k_out(const u16* __restrict__ h, const int* __restrict__ idx,
                                             const float* __restrict__ fc3w,
                                             const float* __restrict__ fc3b,
                                             float* __restrict__ out, int M) {
    int w = threadIdx.x >> 6;
    int lane = threadIdx.x & 63;
    int row = blockIdx.x * 4 + w;
    if (row >= M) return;
    int n = idx[row];
    u32 pair = *(const u32*)&h[(size_t)n * 128 + lane * 2];
    float v0 = __uint_as_float((pair & 0xFFFFu) << 16);
    float v1 = __uint_as_float((pair >> 16) << 16);
    float4 wv = *(const float4*)&fc3w[lane * 4];
    float s0 = v0 * wv.x + v1 * wv.z;
    float s1 = v0 * wv.y + v1 * wv.w;
    for (int off = 32; off >= 1; off >>= 1) {
        s0 += __shfl_xor(s0, off, 64);
        s1 += __shfl_xor(s1, off, 64);
    }
    if (lane == 0) {
        out[row * 2] = s0 + fc3b[0];
        out[row * 2 + 1] = s1 + fc3b[1];
    }
}

// ---------------- launch ----------------

extern "C" void kernel_launch(void* const* d_in, const int* in_sizes, int n_in,
                              void* d_out, int out_size, void* d_ws, size_t ws_size,
                              hipStream_t stream) {
    const float* vf    = (const float*)d_in[0];
    const float* tf    = (const float*)d_in[1];
    const float* fc1w  = (const float*)d_in[2];
    const float* fc1b  = (const float*)d_in[3];
    const float* fc2w  = (const float*)d_in[4];
    const float* fc2b  = (const float*)d_in[5];
    const float* reluw = (const float*)d_in[6];
    const float* relub = (const float*)d_in[7];
    const float* w1rel = (const float*)d_in[8];
    const float* w1root= (const float*)d_in[9];
    const float* b1    = (const float*)d_in[10];
    const float* w2rel = (const float*)d_in[11];
    const float* w2root= (const float*)d_in[12];
    const float* b2    = (const float*)d_in[13];
    const float* fc3w  = (const float*)d_in[14];
    const float* fc3b  = (const float*)d_in[15];
    const int* ei      = (const int*)d_in[16];
    const int* et      = (const int*)d_in[17];
    const int* idx     = (const int*)d_in[18];
    float* out = (float*)d_out;

    char* W = (char*)d_ws;
    const size_t OFF_WTIN  = 0;
    const size_t OFF_WT1   = 204800;
    const size_t OFF_WT2   = 335872;
    const size_t OFF_BCOMB = 466944;
    const size_t OFF_DEGN  = 467456;
    const size_t OFF_CUR   = 667456;
    const size_t OFF_DEGR  = 867456;
    const size_t OFF_CNT   = 1467456;
    const size_t OFF_BASE  = 1467712;
    const size_t OFF_NORM  = 1667712;
    const size_t OFF_ELIST = 2267712;
    const size_t OFF_A     = 4667712;
    const size_t OFF_H0    = 43067712;
    const size_t OFF_H1    = 55867712;
    const size_t OFF_H2    = 68667712;
    const size_t OFF_VFPAD = 81467712;

    u16* WTin   = (u16*)(W + OFF_WTIN);
    u16* WT1    = (u16*)(W + OFF_WT1);
    u16* WT2    = (u16*)(W + OFF_WT2);
    float* bcomb= (float*)(W + OFF_BCOMB);
    int* degn   = (int*)(W + OFF_DEGN);
    int* cur    = (int*)(W + OFF_CUR);
    int* degr   = (int*)(W + OFF_DEGR);
    int* cnt    = (int*)(W + OFF_CNT);
    int* base   = (int*)(W + OFF_BASE);
    float* normf= (float*)(W + OFF_NORM);
    int* elist  = (int*)(W + OFF_ELIST);
    u16* Abuf   = (u16*)(W + OFF_A);
    u16* h0     = (u16*)(W + OFF_H0);
    u16* h1     = (u16*)(W + OFF_H1);
    u16* h2     = (u16*)(W + OFF_H2);
    float* vfp  = (float*)(W + OFF_VFPAD);

    const int GRID_GEMM = (NN + 63) / 64;   // 782 blocks

    k_zero<<<(250001 + 255) / 256, 256, 0, stream>>>(degn, 250001);
    k_padvf<<<(NN * 32 + 255) / 256, 256, 0, stream>>>(vf, vfp);

    k_win<<<800, 128, 0, stream>>>(fc1w, fc2w, reluw, WTin);
    k_bcomb<<<1, 128, 0, stream>>>(fc1b, fc2b, relub, reluw, bcomb);
    k_wrg<<<512, 128, 0, stream>>>(w1rel, w1root, WT1);
    k_wrg<<<512, 128, 0, stream>>>(w2rel, w2root, WT2);

    k_gemm<float, 24, 1, true><<<GRID_GEMM, 256, 0, stream>>>(
        tf, 768, vfp, 32, WTin, 800, bcomb, h0, NN);

    k_hist<<<(NE + 255) / 256, 256, 0, stream>>>(ei, et, degn, degr);
    k_alloc<<<(NN + 255) / 256, 256, 0, stream>>>(degn, base, cnt);
    k_norm<<<(3 * NN + 255) / 256, 256, 0, stream>>>(degr, normf);
    k_fill<<<(NE + 255) / 256, 256, 0, stream>>>(ei, et, base, cur, elist);

    k_agg<<<NN, 64, 0, stream>>>(h0, Abuf, elist, base, degn, normf);
    k_gemm<u16, 12, 4, false><<<GRID_GEMM, 256, 0, stream>>>(
        Abuf, 384, h0, 128, WT1, 512, b1, h1, NN);

    k_agg<<<NN, 64, 0, stream>>>(h1, Abuf, elist, base, degn, normf);
    k_gemm<u16, 12, 4, false><<<GRID_GEMM, 256, 0, stream>>>(
        Abuf, 384, h1, 128, WT2, 512, b2, h2, NN);

    k_out<<<(10000 + 3) / 4, 256, 0, stream>>>(h2, idx, fc3w, fc3b, out, 10000);
}

// Round 9
// 292.667 us; speedup vs baseline: 1.4562x; 1.0254x over previous
//
#include <hip/hip_runtime.h>
#include <hip/hip_bf16.h>

typedef __attribute__((ext_vector_type(8))) short s16x8;
typedef __attribute__((ext_vector_type(4))) float f32x4;
typedef unsigned short u16;
typedef unsigned int u32;

constexpr int NN = 50000;
constexpr int NE = 600000;

__device__ inline u16 f2b(float x) {
    __hip_bfloat16 h = __float2bfloat16(x);
    return *(u16*)&h;
}

__device__ inline s16x8 pack8(float4 a, float4 b) {
    s16x8 r;
    r[0] = (short)f2b(a.x); r[1] = (short)f2b(a.y);
    r[2] = (short)f2b(a.z); r[3] = (short)f2b(a.w);
    r[4] = (short)f2b(b.x); r[5] = (short)f2b(b.y);
    r[6] = (short)f2b(b.z); r[7] = (short)f2b(b.w);
    return r;
}

// async global->LDS DMA, 16B per lane: LDS dst = wave-uniform base + lane*16.
__device__ inline void gl_lds16(const void* gptr, void* lptr) {
    __builtin_amdgcn_global_load_lds(
        (const __attribute__((address_space(1))) char*)gptr,
        (__attribute__((address_space(3))) char*)lptr, 16, 0, 0);
}

template <int N> __device__ inline void vmwait() {
    asm volatile("s_waitcnt vmcnt(%0)" :: "n"(N) : "memory");
}
__device__ inline void barrier_nodrains() {
    __builtin_amdgcn_sched_barrier(0);
    __builtin_amdgcn_s_barrier();
    __builtin_amdgcn_sched_barrier(0);
}

// ---------------- misc small kernels ----------------

__global__ void k_zero(int* __restrict__ p, int n) {
    int i = blockIdx.x * 256 + threadIdx.x;
    if (i < n) p[i] = 0;
}

__global__ void k_padvf(const float* __restrict__ vf, float* __restrict__ vp) {
    int i = blockIdx.x * 256 + threadIdx.x;
    if (i < NN * 32) {
        int n = i >> 5, c = i & 31;
        vp[i] = c < 16 ? vf[n * 16 + c] : 0.f;
    }
}

// WTin[c][k], k<768: (fc2_w @ relu_w_bot)^T ; 768..783: (fc1_w @ relu_w_top)^T ; 784..799: 0
__global__ void k_win(const float* __restrict__ fc1w, const float* __restrict__ fc2w,
                      const float* __restrict__ reluw, u16* __restrict__ WTin) {
    int c = threadIdx.x;
    int k = blockIdx.x;
    float s = 0.f;
    if (k < 768) {
        for (int j = 0; j < 128; ++j) s += fc2w[k * 128 + j] * reluw[(128 + j) * 128 + c];
    } else if (k < 784) {
        int kk = k - 768;
        for (int j = 0; j < 128; ++j) s += fc1w[kk * 128 + j] * reluw[j * 128 + c];
    }
    WTin[c * 800 + k] = f2b(s);
}

__global__ void k_bcomb(const float* __restrict__ fc1b, const float* __restrict__ fc2b,
                        const float* __restrict__ relub, const float* __restrict__ reluw,
                        float* __restrict__ bcomb) {
    int c = threadIdx.x;
    float s = relub[c];
    for (int j = 0; j < 128; ++j) {
        s += fc1b[j] * reluw[j * 128 + c];
        s += fc2b[j] * reluw[(128 + j) * 128 + c];
    }
    bcomb[c] = s;
}

// WT[c][s] = stacked [wrel(3x128x128); wroot(128x128)] transposed, bf16
__global__ void k_wrg(const float* __restrict__ wrel, const float* __restrict__ wroot,
                      u16* __restrict__ WT) {
    int c = threadIdx.x;
    int s = blockIdx.x;
    float v = (s < 384) ? wrel[(size_t)s * 128 + c] : wroot[(size_t)(s - 384) * 128 + c];
    WT[c * 512 + s] = f2b(v);
}

// ---------------- CSR build ----------------

__global__ void k_hist(const int* __restrict__ ei, const int* __restrict__ et,
                       int* __restrict__ deg_node, int* __restrict__ deg_rel) {
    int e = blockIdx.x * 256 + threadIdx.x;
    if (e >= NE) return;
    int dst = ei[NE + e];
    int r = et[e];
    atomicAdd(&deg_node[dst], 1);
    atomicAdd(&deg_rel[r * NN + dst], 1);
}

__global__ void k_alloc(const int* __restrict__ deg_node, int* __restrict__ baseoff,
                        int* __restrict__ counter) {
    int i = blockIdx.x * 256 + threadIdx.x;
    int lane = threadIdx.x & 63;
    int d = (i < NN) ? deg_node[i] : 0;
    int scan = d;
    for (int off = 1; off < 64; off <<= 1) {
        int t = __shfl_up(scan, off, 64);
        if (lane >= off) scan += t;
    }
    int total = __shfl(scan, 63, 64);
    int wbase = 0;
    if (lane == 63) wbase = atomicAdd(counter, total);
    wbase = __shfl(wbase, 63, 64);
    if (i < NN) baseoff[i] = wbase + scan - d;
}

__global__ void k_norm(const int* __restrict__ deg_rel, float* __restrict__ normf) {
    int i = blockIdx.x * 256 + threadIdx.x;
    if (i < 3 * NN) normf[i] = 1.0f / (float)max(deg_rel[i], 1);
}

__global__ void k_fill(const int* __restrict__ ei, const int* __restrict__ et,
                       const int* __restrict__ baseoff, int* __restrict__ cursor,
                       int* __restrict__ elist) {
    int e = blockIdx.x * 256 + threadIdx.x;
    if (e >= NE) return;
    int dst = ei[NE + e];
    int src = ei[e];
    int r = et[e];
    int pos = atomicAdd(&cursor[dst], 1);
    elist[baseoff[dst] + pos] = src | (r << 20);
}

// ---------------- aggregation (gather over CSR): 1 wave per node ----------------

__global__ __launch_bounds__(64) void k_agg(const u16* __restrict__ x, u16* __restrict__ A,
                                            const int* __restrict__ elist,
                                            const int* __restrict__ baseoff,
                                            const int* __restrict__ deg_node,
                                            const float* __restrict__ normf) {
    int n = blockIdx.x;
    int lane = threadIdx.x;
    float a0x = 0.f, a0y = 0.f, a1x = 0.f, a1y = 0.f, a2x = 0.f, a2y = 0.f;
    int nb = deg_node[n];
    int b0 = baseoff[n];
    for (int i = 0; i < nb; ++i) {
        int p = elist[b0 + i];
        int src = p & 0xFFFFF;
        int r = p >> 20;
        u32 pair = *(const u32*)&x[(size_t)src * 128 + lane * 2];
        float vx = __uint_as_float((pair & 0xFFFFu) << 16);
        float vy = __uint_as_float((pair >> 16) << 16);
        if (r == 0)      { a0x += vx; a0y += vy; }
        else if (r == 1) { a1x += vx; a1y += vy; }
        else             { a2x += vx; a2y += vy; }
    }
    float n0 = normf[n], n1 = normf[NN + n], n2 = normf[2 * NN + n];
    u32* Ao = (u32*)&A[(size_t)n * 384];
    Ao[lane]        = (u32)f2b(a0x * n0) | ((u32)f2b(a0y * n0) << 16);
    Ao[64 + lane]   = (u32)f2b(a1x * n1) | ((u32)f2b(a1y * n1) << 16);
    Ao[128 + lane]  = (u32)f2b(a2x * n2) | ((u32)f2b(a2y * n2) << 16);
}

// ---------------- GEMM: [N, 32*(K1T+K2T)] x WT^T -> [N,128] bf16 ----------------
// m97 geometry: BM=128, BK=32, 256 thr = 4 waves in 2x2, each wave a 64x64
// output quadrant (4x4 frags, 16 MFMA per k-step => 1 MFLOP/block/k-step).
// 3 LDS buffers, prefetch depth 2, counted vmcnt(OPW) at the barrier (never 0
// until the final k-step). Per iteration j:
//   vmcnt(OPW) -> stage(j) landed, stage(j+1) in flight
//   s_barrier  -> tile j visible to all; buf[(j+2)%3]'s readers (compute j-1) done
//   stage(j+2) -> issue next DMAs (fly under compute)
//   compute(j) -> 12 ds_read_b128 + 16 MFMA per wave
// Swizzled LDS (both-sides involution), verified rounds 7/8.

template <typename TA, int K1T, int K2T, bool LRELU>
__global__ __launch_bounds__(256) void k_gemm(const TA* __restrict__ A1, int lda1,
                                              const TA* __restrict__ A2, int lda2,
                                              const u16* __restrict__ WT, int ldwt,
                                              const float* __restrict__ bias,
                                              u16* __restrict__ out, int N) {
    constexpr int KT = K1T + K2T;
    constexpr int ABYTES = 128 * 32 * (int)sizeof(TA);
    constexpr int TILEB = ABYTES + 8192;
    constexpr int OPW = (sizeof(TA) == 4) ? 6 : 4;   // DMA instrs per wave per stage
    __shared__ alignas(128) char lds[3][TILEB];

    const int tid = threadIdx.x;
    const int m0 = blockIdx.x * 128;
    const int w = tid >> 6, lane = tid & 63;
    const int wr = w >> 1, wc = w & 1;
    const int lq = lane >> 4, lr = lane & 15;

    auto stage = [&](int j) {
        char* base = lds[j % 3];
        int kt = j;
        // ---- A tile [128 rows][32 cols] ----
        if constexpr (sizeof(TA) == 4) {
#pragma unroll
            for (int jj = 0; jj < 4; ++jj) {
                int row = w * 32 + jj * 8 + (lane >> 3);
                int s = lane & 7;
                int chunk = s ^ (row & 7);
                int rg = min(m0 + row, N - 1);
                const float* g;
                if (kt < K1T) g = (const float*)A1 + (size_t)rg * lda1 + kt * 32 + chunk * 4;
                else          g = (const float*)A2 + (size_t)rg * lda2 + (kt - K1T) * 32 + chunk * 4;
                gl_lds16(g, base + w * 4096 + jj * 1024);
            }
        } else {
#pragma unroll
            for (int jj = 0; jj < 2; ++jj) {
                int row = w * 32 + jj * 16 + (lane >> 2);
                int s = lane & 3;
                int chunk = s ^ ((row >> 1) & 3);
                int rg = min(m0 + row, N - 1);
                const u16* g;
                if (kt < K1T) g = (const u16*)A1 + (size_t)rg * lda1 + kt * 32 + chunk * 8;
                else          g = (const u16*)A2 + (size_t)rg * lda2 + (kt - K1T) * 32 + chunk * 8;
                gl_lds16(g, base + w * 2048 + jj * 1024);
            }
        }
        // ---- B tile [128 cols][32 k] ----
#pragma unroll
        for (int jj = 0; jj < 2; ++jj) {
            int col = w * 32 + jj * 16 + (lane >> 2);
            int s = lane & 3;
            int chunk = s ^ ((col >> 1) & 3);
            const u16* g = WT + (size_t)col * ldwt + kt * 32 + chunk * 8;
            gl_lds16(g, base + ABYTES + w * 2048 + jj * 1024);
        }
    };

    f32x4 acc[4][4] = {};

    auto compute = [&](int j) {
        char* base = lds[j % 3];
        s16x8 af[4];
#pragma unroll
        for (int i = 0; i < 4; ++i) {
            int row = wr * 64 + i * 16 + lr;
            if constexpr (sizeof(TA) == 4) {
                int m = row & 7;
                float4 f0 = *(const float4*)(base + row * 128 + (((2 * lq) ^ m) * 16));
                float4 f1 = *(const float4*)(base + row * 128 + (((2 * lq + 1) ^ m) * 16));
                af[i] = pack8(f0, f1);
            } else {
                int sl = lq ^ ((row >> 1) & 3);
                af[i] = *(const s16x8*)(base + row * 64 + sl * 16);
            }
        }
#pragma unroll
        for (int j4 = 0; j4 < 4; ++j4) {
            int col = wc * 64 + j4 * 16 + lr;
            int sl = lq ^ ((col >> 1) & 3);
            s16x8 bf = *(const s16x8*)(base + ABYTES + col * 64 + sl * 16);
#pragma unroll
            for (int i = 0; i < 4; ++i)
                acc[i][j4] = __builtin_amdgcn_mfma_f32_16x16x32_bf16(af[i], bf, acc[i][j4], 0, 0, 0);
        }
    };

    stage(0); stage(1);
#pragma unroll 1
    for (int j = 0; j < KT - 1; ++j) {
        vmwait<OPW>();             // stage(j) landed; stage(j+1) stays in flight
        barrier_nodrains();
        if (j + 2 < KT) stage(j + 2);
        compute(j);
    }
    vmwait<0>();
    barrier_nodrains();
    compute(KT - 1);

#pragma unroll
    for (int i = 0; i < 4; ++i) {
#pragma unroll
        for (int q = 0; q < 4; ++q) {
            int grow = m0 + wr * 64 + i * 16 + lq * 4 + q;
            if (grow < N) {
#pragma unroll
                for (int j = 0; j < 4; ++j) {
                    int col = wc * 64 + j * 16 + lr;
                    float v = acc[i][j][q] + bias[col];
                    if (LRELU) v = v > 0.f ? v : 0.01f * v;
                    out[(size_t)grow * 128 + col] = f2b(v);
                }
            }
        }
    }
}

// ---------------- final gather + classifier ----------------

__global__ __launch_bounds__(256) void k_out(const u16* __restrict__ h, const int* __restrict__ idx,
                                             const float* __restrict__ fc3w,
                                             const float* __restrict__ fc3b,
                                             float* __restrict__ out, int M) {
    int w = threadIdx.x >> 6;
    int lane = threadIdx.x & 63;
    int row = blockIdx.x * 4 + w;
    if (row >= M) return;
    int n = idx[row];
    u32 pair = *(const u32*)&h[(size_t)n * 128 + lane * 2];
    float v0 = __uint_as_float((pair & 0xFFFFu) << 16);
    float v1 = __uint_as_float((pair >> 16) << 16);
    float4 wv = *(const float4*)&fc3w[lane * 4];
    float s0 = v0 * wv.x + v1 * wv.z;
    float s1 = v0 * wv.y + v1 * wv.w;
    for (int off = 32; off >= 1; off >>= 1) {
        s0 += __shfl_xor(s0, off, 64);
        s1 += __shfl_xor(s1, off, 64);
    }
    if (lane == 0) {
        out[row * 2] = s0 + fc3b[0];
        out[row * 2 + 1] = s1 + fc3b[1];
    }
}

// ---------------- launch ----------------

extern "C" void kernel_launch(void* const* d_in, const int* in_sizes, int n_in,
                              void* d_out, int out_size, void* d_ws, size_t ws_size,
                              hipStream_t stream) {
    const float* vf    = (const float*)d_in[0];
    const float* tf    = (const float*)d_in[1];
    const float* fc1w  = (const float*)d_in[2];
    const float* fc1b  = (const float*)d_in[3];
    const float* fc2w  = (const float*)d_in[4];
    const float* fc2b  = (const float*)d_in[5];
    const float* reluw = (const float*)d_in[6];
    const float* relub = (const float*)d_in[7];
    const float* w1rel = (const float*)d_in[8];
    const float* w1root= (const float*)d_in[9];
    const float* b1    = (const float*)d_in[10];
    const float* w2rel = (const float*)d_in[11];
    const float* w2root= (const float*)d_in[12];
    const float* b2    = (const float*)d_in[13];
    const float* fc3w  = (const float*)d_in[14];
    const float* fc3b  = (const float*)d_in[15];
    const int* ei      = (const int*)d_in[16];
    const int* et      = (const int*)d_in[17];
    const int* idx     = (const int*)d_in[18];
    float* out = (float*)d_out;

    char* W = (char*)d_ws;
    const size_t OFF_WTIN  = 0;
    const size_t OFF_WT1   = 204800;
    const size_t OFF_WT2   = 335872;
    const size_t OFF_BCOMB = 466944;
    const size_t OFF_DEGN  = 467456;
    const size_t OFF_CUR   = 667456;
    const size_t OFF_DEGR  = 867456;
    const size_t OFF_CNT   = 1467456;
    const size_t OFF_BASE  = 1467712;
    const size_t OFF_NORM  = 1667712;
    const size_t OFF_ELIST = 2267712;
    const size_t OFF_A     = 4667712;
    const size_t OFF_H0    = 43067712;
    const size_t OFF_H1    = 55867712;
    const size_t OFF_H2    = 68667712;
    const size_t OFF_VFPAD = 81467712;

    u16* WTin   = (u16*)(W + OFF_WTIN);
    u16* WT1    = (u16*)(W + OFF_WT1);
    u16* WT2    = (u16*)(W + OFF_WT2);
    float* bcomb= (float*)(W + OFF_BCOMB);
    int* degn   = (int*)(W + OFF_DEGN);
    int* cur    = (int*)(W + OFF_CUR);
    int* degr   = (int*)(W + OFF_DEGR);
    int* cnt    = (int*)(W + OFF_CNT);
    int* base   = (int*)(W + OFF_BASE);
    float* normf= (float*)(W + OFF_NORM);
    int* elist  = (int*)(W + OFF_ELIST);
    u16* Abuf   = (u16*)(W + OFF_A);
    u16* h0     = (u16*)(W + OFF_H0);
    u16* h1     = (u16*)(W + OFF_H1);
    u16* h2     = (u16*)(W + OFF_H2);
    float* vfp  = (float*)(W + OFF_VFPAD);

    const int GRID_GEMM = (NN + 127) / 128;   // 391 blocks, all co-resident

    k_zero<<<(250001 + 255) / 256, 256, 0, stream>>>(degn, 250001);
    k_padvf<<<(NN * 32 + 255) / 256, 256, 0, stream>>>(vf, vfp);

    k_win<<<800, 128, 0, stream>>>(fc1w, fc2w, reluw, WTin);
    k_bcomb<<<1, 128, 0, stream>>>(fc1b, fc2b, relub, reluw, bcomb);
    k_wrg<<<512, 128, 0, stream>>>(w1rel, w1root, WT1);
    k_wrg<<<512, 128, 0, stream>>>(w2rel, w2root, WT2);

    k_gemm<float, 24, 1, true><<<GRID_GEMM, 256, 0, stream>>>(
        tf, 768, vfp, 32, WTin, 800, bcomb, h0, NN);

    k_hist<<<(NE + 255) / 256, 256, 0, stream>>>(ei, et, degn, degr);
    k_alloc<<<(NN + 255) / 256, 256, 0, stream>>>(degn, base, cnt);
    k_norm<<<(3 * NN + 255) / 256, 256, 0, stream>>>(degr, normf);
    k_fill<<<(NE + 255) / 256, 256, 0, stream>>>(ei, et, base, cur, elist);

    k_agg<<<NN, 64, 0, stream>>>(h0, Abuf, elist, base, degn, normf);
    k_gemm<u16, 12, 4, false><<<GRID_GEMM, 256, 0, stream>>>(
        Abuf, 384, h0, 128, WT1, 512, b1, h1, NN);

    k_agg<<<NN, 64, 0, stream>>>(h1, Abuf, elist, base, degn, normf);
    k_gemm<u16, 12, 4, false><<<GRID_GEMM, 256, 0, stream>>>(
        Abuf, 384, h1, 128, WT2, 512, b2, h2, NN);

    k_out<<<(10000 + 3) / 4, 256, 0, stream>>>(h2, idx, fc3w, fc3b, out, 10000);
}